// Round 1
// baseline (1925.090 us; speedup 1.0000x reference)
//
#include <hip/hip_runtime.h>

// Problem: B=2, T=2048, C=1024, H=16, hd=64. All fp32 in/out.
// ws layout (fp32): q[2*16*2048*64] | k[...] | v[...] | y[4096*1024]  = 64 MB total.

#define T_SEQ 2048
#define C_DIM 1024
#define NH    16
#define HD    64
#define BT    4096   // B*T

// ---------------- GEMM + bias + scatter to q/k/v [B,H,T,hd] ----------------
__global__ __launch_bounds__(256) void qkv_gemm(const float* __restrict__ X,
                                                const float* __restrict__ W,
                                                const float* __restrict__ bias,
                                                float* __restrict__ qb,
                                                float* __restrict__ kb,
                                                float* __restrict__ vb) {
    const int K = 1024, N = 3072;
    __shared__ float As[64][36];   // stride 36: broadcast/2-way reads
    __shared__ float Bs[32][68];   // stride 68: float4-aligned, 2-way reads
    const int tid = threadIdx.x;
    const int tx = tid & 15, ty = tid >> 4;
    const int row0 = blockIdx.y << 6;
    const int col0 = blockIdx.x << 6;
    float acc[4][4] = {};
    for (int k0 = 0; k0 < K; k0 += 32) {
#pragma unroll
        for (int i = 0; i < 2; i++) {                 // A tile 64x32
            int f = (i << 8) + tid;
            int r = f >> 3, c = (f & 7) << 2;
            *(float4*)&As[r][c] = *(const float4*)(X + (size_t)(row0 + r) * K + k0 + c);
        }
#pragma unroll
        for (int i = 0; i < 2; i++) {                 // B tile 32x64
            int f = (i << 8) + tid;
            int r = f >> 4, c = (f & 15) << 2;
            *(float4*)&Bs[r][c] = *(const float4*)(W + (size_t)(k0 + r) * N + col0 + c);
        }
        __syncthreads();
#pragma unroll
        for (int kk = 0; kk < 32; kk++) {
            float a[4];
#pragma unroll
            for (int i = 0; i < 4; i++) a[i] = As[(ty << 2) + i][kk];
            float4 bq = *(float4*)&Bs[kk][tx << 2];
            float bv[4] = {bq.x, bq.y, bq.z, bq.w};
#pragma unroll
            for (int i = 0; i < 4; i++)
#pragma unroll
                for (int j = 0; j < 4; j++)
                    acc[i][j] = fmaf(a[i], bv[j], acc[i][j]);
        }
        __syncthreads();
    }
    // epilogue: +bias, scatter. col n -> head h=n/192, r=n%192: sel=r/64, d=r%64
#pragma unroll
    for (int i = 0; i < 4; i++) {
        int m = row0 + (ty << 2) + i;
        int bidx = m >> 11, t = m & 2047;
#pragma unroll
        for (int j = 0; j < 4; j++) {
            int n = col0 + (tx << 2) + j;
            float val = acc[i][j] + bias[n];
            int h = n / 192, r = n % 192;
            int sel = r >> 6, d = r & 63;
            float* dst = (sel == 0) ? qb : ((sel == 1) ? kb : vb);
            dst[(((size_t)bidx * NH + h) * T_SEQ + t) * HD + d] = val;
        }
    }
}

// ---------------- flash-style causal attention, fp32 ----------------
// grid: (qtile=32, bh=32), block 256. Thread owns rows ty*4+i, S-cols tx+16j,
// O-cols tx*4+j. Row softmax reduced over the 16-lane segment holding the row.
__global__ __launch_bounds__(256) void attn(const float* __restrict__ qb,
                                            const float* __restrict__ kb,
                                            const float* __restrict__ vb,
                                            float* __restrict__ y) {
    __shared__ float Qs[64][68];
    __shared__ float Ks[64][68];   // reused to hold P after S is consumed
    __shared__ float Vs[64][68];
    const int tid = threadIdx.x;
    const int tx = tid & 15, ty = tid >> 4;
    const int qt = blockIdx.x;
    const int bh = blockIdx.y;
    const size_t base = (size_t)bh * T_SEQ * HD;
    const int q0 = qt << 6;
    const float NEG_INF = -__builtin_inff();

#pragma unroll
    for (int i = 0; i < 4; i++) {                     // Q tile 64x64
        int f = (i << 8) + tid;
        int r = f >> 4, c = (f & 15) << 2;
        *(float4*)&Qs[r][c] = *(const float4*)(qb + base + (size_t)(q0 + r) * HD + c);
    }
    float o[4][4] = {};
    float m_prev[4] = {NEG_INF, NEG_INF, NEG_INF, NEG_INF};
    float l_run[4] = {};

    for (int kt = 0; kt <= qt; kt++) {
        const int k0 = kt << 6;
        __syncthreads();   // prior-iter Ks/Vs reads done (covers Q-write for kt=0)
#pragma unroll
        for (int i = 0; i < 4; i++) {                 // K,V tiles 64x64
            int f = (i << 8) + tid;
            int r = f >> 4, c = (f & 15) << 2;
            *(float4*)&Ks[r][c] = *(const float4*)(kb + base + (size_t)(k0 + r) * HD + c);
            *(float4*)&Vs[r][c] = *(const float4*)(vb + base + (size_t)(k0 + r) * HD + c);
        }
        __syncthreads();

        // S = Q K^T (this thread: rows ty*4+i, cols tx+16j)
        float s[4][4] = {};
#pragma unroll
        for (int d0 = 0; d0 < 64; d0 += 4) {
            float4 q4[4], k4[4];
#pragma unroll
            for (int i = 0; i < 4; i++) q4[i] = *(float4*)&Qs[(ty << 2) + i][d0];
#pragma unroll
            for (int j = 0; j < 4; j++) k4[j] = *(float4*)&Ks[tx + (j << 4)][d0];
#pragma unroll
            for (int i = 0; i < 4; i++)
#pragma unroll
                for (int j = 0; j < 4; j++)
                    s[i][j] += q4[i].x * k4[j].x + q4[i].y * k4[j].y +
                               q4[i].z * k4[j].z + q4[i].w * k4[j].w;
        }

        // mask + scale + online softmax (per-row, shfl over 16-lane segment)
#pragma unroll
        for (int i = 0; i < 4; i++) {
            int qi = q0 + (ty << 2) + i;
            float mx = NEG_INF;
#pragma unroll
            for (int j = 0; j < 4; j++) {
                int ki = k0 + tx + (j << 4);
                s[i][j] = (ki <= qi) ? s[i][j] * 0.125f : NEG_INF;
                mx = fmaxf(mx, s[i][j]);
            }
#pragma unroll
            for (int off = 8; off; off >>= 1) mx = fmaxf(mx, __shfl_xor(mx, off, 16));
            float m_new = fmaxf(m_prev[i], mx);       // finite: diagonal always unmasked
            float alpha = __expf(m_prev[i] - m_new);
            float ssum = 0.f;
#pragma unroll
            for (int j = 0; j < 4; j++) { s[i][j] = __expf(s[i][j] - m_new); ssum += s[i][j]; }
#pragma unroll
            for (int off = 8; off; off >>= 1) ssum += __shfl_xor(ssum, off, 16);
            l_run[i] = l_run[i] * alpha + ssum;
            m_prev[i] = m_new;
#pragma unroll
            for (int j = 0; j < 4; j++) o[i][j] *= alpha;
        }

        __syncthreads();                // all Ks reads done -> reuse for P
#pragma unroll
        for (int i = 0; i < 4; i++)
#pragma unroll
            for (int j = 0; j < 4; j++)
                Ks[(ty << 2) + i][tx + (j << 4)] = s[i][j];
        __syncthreads();

        // O += P @ V   (P from LDS, rows broadcast; V float4, 2-way)
#pragma unroll
        for (int c0 = 0; c0 < 64; c0 += 4) {
            float4 pr[4], vv[4];
#pragma unroll
            for (int i = 0; i < 4; i++) pr[i] = *(float4*)&Ks[(ty << 2) + i][c0];
#pragma unroll
            for (int u = 0; u < 4; u++) vv[u] = *(float4*)&Vs[c0 + u][tx << 2];
#pragma unroll
            for (int i = 0; i < 4; i++) {
                o[i][0] += pr[i].x * vv[0].x + pr[i].y * vv[1].x + pr[i].z * vv[2].x + pr[i].w * vv[3].x;
                o[i][1] += pr[i].x * vv[0].y + pr[i].y * vv[1].y + pr[i].z * vv[2].y + pr[i].w * vv[3].y;
                o[i][2] += pr[i].x * vv[0].z + pr[i].y * vv[1].z + pr[i].z * vv[2].z + pr[i].w * vv[3].z;
                o[i][3] += pr[i].x * vv[0].w + pr[i].y * vv[1].w + pr[i].z * vv[2].w + pr[i].w * vv[3].w;
            }
        }
    }

    // y[b, t, h*64 + d]  (merge heads back to [B,T,C])
    const int b = bh >> 4, h = bh & 15;
#pragma unroll
    for (int i = 0; i < 4; i++) {
        float inv = 1.0f / l_run[i];
        int t = q0 + (ty << 2) + i;
        float4 o4 = make_float4(o[i][0] * inv, o[i][1] * inv, o[i][2] * inv, o[i][3] * inv);
        *(float4*)(y + ((size_t)b * T_SEQ + t) * C_DIM + h * HD + (tx << 2)) = o4;
    }
}

// ---------------- out = y @ w_out + b_out ----------------
__global__ __launch_bounds__(256) void out_gemm(const float* __restrict__ Y,
                                                const float* __restrict__ W,
                                                const float* __restrict__ bias,
                                                float* __restrict__ out) {
    const int K = 1024, N = 1024;
    __shared__ float As[64][36];
    __shared__ float Bs[32][68];
    const int tid = threadIdx.x;
    const int tx = tid & 15, ty = tid >> 4;
    const int row0 = blockIdx.y << 6;
    const int col0 = blockIdx.x << 6;
    float acc[4][4] = {};
    for (int k0 = 0; k0 < K; k0 += 32) {
#pragma unroll
        for (int i = 0; i < 2; i++) {
            int f = (i << 8) + tid;
            int r = f >> 3, c = (f & 7) << 2;
            *(float4*)&As[r][c] = *(const float4*)(Y + (size_t)(row0 + r) * K + k0 + c);
        }
#pragma unroll
        for (int i = 0; i < 2; i++) {
            int f = (i << 8) + tid;
            int r = f >> 4, c = (f & 15) << 2;
            *(float4*)&Bs[r][c] = *(const float4*)(W + (size_t)(k0 + r) * N + col0 + c);
        }
        __syncthreads();
#pragma unroll
        for (int kk = 0; kk < 32; kk++) {
            float a[4];
#pragma unroll
            for (int i = 0; i < 4; i++) a[i] = As[(ty << 2) + i][kk];
            float4 bq = *(float4*)&Bs[kk][tx << 2];
            float bv[4] = {bq.x, bq.y, bq.z, bq.w};
#pragma unroll
            for (int i = 0; i < 4; i++)
#pragma unroll
                for (int j = 0; j < 4; j++)
                    acc[i][j] = fmaf(a[i], bv[j], acc[i][j]);
        }
        __syncthreads();
    }
    const float4 b4 = *(const float4*)(bias + col0 + (tx << 2));
#pragma unroll
    for (int i = 0; i < 4; i++) {
        int m = row0 + (ty << 2) + i;
        float4 o4 = make_float4(acc[i][0] + b4.x, acc[i][1] + b4.y,
                                acc[i][2] + b4.z, acc[i][3] + b4.w);
        *(float4*)(out + (size_t)m * N + col0 + (tx << 2)) = o4;
    }
}

extern "C" void kernel_launch(void* const* d_in, const int* in_sizes, int n_in,
                              void* d_out, int out_size, void* d_ws, size_t ws_size,
                              hipStream_t stream) {
    (void)in_sizes; (void)n_in; (void)out_size; (void)ws_size;
    const float* x     = (const float*)d_in[0];
    const float* w_qkv = (const float*)d_in[1];
    const float* b_qkv = (const float*)d_in[2];
    const float* w_out = (const float*)d_in[3];
    const float* b_out = (const float*)d_in[4];
    float* out = (float*)d_out;

    const size_t per = (size_t)BT * C_DIM;   // 4,194,304 floats = 16 MB
    float* qb = (float*)d_ws;
    float* kb = qb + per;
    float* vb = kb + per;
    float* yb = vb + per;                    // total 64 MB of ws

    qkv_gemm<<<dim3(48, 64), 256, 0, stream>>>(x, w_qkv, b_qkv, qb, kb, vb);
    attn    <<<dim3(32, 32), 256, 0, stream>>>(qb, kb, vb, yb);
    out_gemm<<<dim3(16, 64), 256, 0, stream>>>(yb, w_out, b_out, out);
}

// Round 2
// 695.612 us; speedup vs baseline: 2.7675x; 2.7675x over previous
//
#include <hip/hip_runtime.h>

// B=2, T=2048, C=1024, H=16, hd=64. fp32 in/out; bf16 MFMA for the two GEMMs.
// ws (64 MB): qb f32 16MB | kb 16MB | vb 16MB | xb/yb bf16 8MB (aliased) |
//             wqkvT bf16 6MB | woutT bf16 2MB

#define T_SEQ 2048
#define C_DIM 1024
#define NH    16
#define HD    64
#define BT    4096

typedef short bf16x8 __attribute__((ext_vector_type(8)));   // 8 bf16 (4 VGPRs)
typedef float floatx4 __attribute__((ext_vector_type(4)));  // MFMA accum

static __device__ __forceinline__ unsigned short f2bf(float f) {
    union { float f; unsigned u; } v; v.f = f;
    unsigned u = v.u;
    return (unsigned short)((u + 0x7FFFu + ((u >> 16) & 1u)) >> 16);
}

// ---------------- fp32 -> bf16 elementwise ----------------
__global__ __launch_bounds__(256) void convert_bf16(const float* __restrict__ in,
                                                    unsigned short* __restrict__ out, int n) {
    int i = (blockIdx.x * 256 + threadIdx.x) * 4;
    const int stride = gridDim.x * 1024;
    for (; i < n; i += stride) {
        float4 f = *(const float4*)(in + i);
        ushort4 o;
        o.x = f2bf(f.x); o.y = f2bf(f.y); o.z = f2bf(f.z); o.w = f2bf(f.w);
        *(ushort4*)(out + i) = o;
    }
}

// ---------------- fp32 [K][N] -> bf16 [N][K] (W^T) ----------------
__global__ __launch_bounds__(256) void transpose_bf16(const float* __restrict__ W,
                                                      unsigned short* __restrict__ Wt,
                                                      int K, int N) {
    __shared__ float tile[64][65];
    const int k0 = blockIdx.y << 6;
    const int n0 = blockIdx.x << 6;
    const int rr = threadIdx.x >> 4;
    const int cc = (threadIdx.x & 15) << 2;
#pragma unroll
    for (int i = 0; i < 4; i++) {
        int r = rr + (i << 4);
        *(float4*)&tile[r][cc] = *(const float4*)(W + (size_t)(k0 + r) * N + n0 + cc);
    }
    __syncthreads();
#pragma unroll
    for (int i = 0; i < 4; i++) {
        int nr = rr + (i << 4);
        ushort4 o;
        o.x = f2bf(tile[cc + 0][nr]);
        o.y = f2bf(tile[cc + 1][nr]);
        o.z = f2bf(tile[cc + 2][nr]);
        o.w = f2bf(tile[cc + 3][nr]);
        *(ushort4*)(Wt + (size_t)(n0 + nr) * K + k0 + cc) = o;
    }
}

// ---------------- bf16 MFMA GEMM: C = A @ Bt^T (+bias), scatter to q/k/v ----
// A [4096][1024] bf16, Bt [3072][1024] bf16. 128x128 tile, BK=32, 4 waves,
// each wave 64x64 = 4x4 MFMA 16x16x32. C layout: col=lane&15, row=quad*4+reg.
__global__ __launch_bounds__(256) void gemm_qkv(const unsigned short* __restrict__ A,
                                                const unsigned short* __restrict__ Bt,
                                                const float* __restrict__ bias,
                                                float* __restrict__ qb,
                                                float* __restrict__ kb,
                                                float* __restrict__ vb) {
    const int K = 1024;
    __shared__ short As[128][40];   // pad 32->40: frag reads hit LDS floor
    __shared__ short Bs[128][40];
    const int tid  = threadIdx.x;
    const int lane = tid & 63, wave = tid >> 6;
    const int ln   = lane & 15, quad = lane >> 4;
    const int wm   = wave & 1,  wn   = wave >> 1;
    const int row0 = blockIdx.y << 7;
    const int col0 = blockIdx.x << 7;
    floatx4 acc[4][4];
#pragma unroll
    for (int i = 0; i < 4; i++)
#pragma unroll
        for (int j = 0; j < 4; j++) acc[i][j] = (floatx4){0.f, 0.f, 0.f, 0.f};

    for (int k0 = 0; k0 < K; k0 += 32) {
#pragma unroll
        for (int cc = 0; cc < 2; cc++) {          // 512 16B-chunks per matrix
            int c = (cc << 8) + tid;
            int r = c >> 2, q = c & 3;
            *(bf16x8*)&As[r][q << 3] = *(const bf16x8*)(A  + (size_t)(row0 + r) * K + k0 + (q << 3));
            *(bf16x8*)&Bs[r][q << 3] = *(const bf16x8*)(Bt + (size_t)(col0 + r) * K + k0 + (q << 3));
        }
        __syncthreads();
        bf16x8 af[4], bfr[4];
#pragma unroll
        for (int t = 0; t < 4; t++) af[t]  = *(bf16x8*)&As[(wm << 6) + (t << 4) + ln][quad << 3];
#pragma unroll
        for (int t = 0; t < 4; t++) bfr[t] = *(bf16x8*)&Bs[(wn << 6) + (t << 4) + ln][quad << 3];
#pragma unroll
        for (int mt = 0; mt < 4; mt++)
#pragma unroll
            for (int nt = 0; nt < 4; nt++)
                acc[mt][nt] = __builtin_amdgcn_mfma_f32_16x16x32_bf16(af[mt], bfr[nt], acc[mt][nt], 0, 0, 0);
        __syncthreads();
    }
    // epilogue: +bias, scatter col n -> h=n/192, sel, d
#pragma unroll
    for (int mt = 0; mt < 4; mt++) {
#pragma unroll
        for (int nt = 0; nt < 4; nt++) {
            int n = col0 + (wn << 6) + (nt << 4) + ln;
            int h = n / 192, r = n % 192;
            int sel = r >> 6, d = r & 63;
            float bv = bias[n];
            float* dst = (sel == 0) ? qb : ((sel == 1) ? kb : vb);
#pragma unroll
            for (int e = 0; e < 4; e++) {
                int m = row0 + (wm << 6) + (mt << 4) + (quad << 2) + e;
                int b = m >> 11, t = m & 2047;
                dst[(((size_t)b * NH + h) * T_SEQ + t) * HD + d] = acc[mt][nt][e] + bv;
            }
        }
    }
}

// ---------------- bf16 MFMA GEMM: out = Y @ WoutT^T + bias (fp32 out) -------
__global__ __launch_bounds__(256) void gemm_out(const unsigned short* __restrict__ A,
                                                const unsigned short* __restrict__ Bt,
                                                const float* __restrict__ bias,
                                                float* __restrict__ out) {
    const int K = 1024, N = 1024;
    __shared__ short As[128][40];
    __shared__ short Bs[128][40];
    const int tid  = threadIdx.x;
    const int lane = tid & 63, wave = tid >> 6;
    const int ln   = lane & 15, quad = lane >> 4;
    const int wm   = wave & 1,  wn   = wave >> 1;
    const int row0 = blockIdx.y << 7;
    const int col0 = blockIdx.x << 7;
    floatx4 acc[4][4];
#pragma unroll
    for (int i = 0; i < 4; i++)
#pragma unroll
        for (int j = 0; j < 4; j++) acc[i][j] = (floatx4){0.f, 0.f, 0.f, 0.f};

    for (int k0 = 0; k0 < K; k0 += 32) {
#pragma unroll
        for (int cc = 0; cc < 2; cc++) {
            int c = (cc << 8) + tid;
            int r = c >> 2, q = c & 3;
            *(bf16x8*)&As[r][q << 3] = *(const bf16x8*)(A  + (size_t)(row0 + r) * K + k0 + (q << 3));
            *(bf16x8*)&Bs[r][q << 3] = *(const bf16x8*)(Bt + (size_t)(col0 + r) * K + k0 + (q << 3));
        }
        __syncthreads();
        bf16x8 af[4], bfr[4];
#pragma unroll
        for (int t = 0; t < 4; t++) af[t]  = *(bf16x8*)&As[(wm << 6) + (t << 4) + ln][quad << 3];
#pragma unroll
        for (int t = 0; t < 4; t++) bfr[t] = *(bf16x8*)&Bs[(wn << 6) + (t << 4) + ln][quad << 3];
#pragma unroll
        for (int mt = 0; mt < 4; mt++)
#pragma unroll
            for (int nt = 0; nt < 4; nt++)
                acc[mt][nt] = __builtin_amdgcn_mfma_f32_16x16x32_bf16(af[mt], bfr[nt], acc[mt][nt], 0, 0, 0);
        __syncthreads();
    }
#pragma unroll
    for (int mt = 0; mt < 4; mt++) {
#pragma unroll
        for (int nt = 0; nt < 4; nt++) {
            int n = col0 + (wn << 6) + (nt << 4) + ln;
            float bv = bias[n];
#pragma unroll
            for (int e = 0; e < 4; e++) {
                int m = row0 + (wm << 6) + (mt << 4) + (quad << 2) + e;
                out[(size_t)m * N + n] = acc[mt][nt][e] + bv;
            }
        }
    }
}

// ---------------- flash-style causal attention, fp32, spill-free ----------
__global__ __launch_bounds__(256, 4) void attn(const float* __restrict__ qb,
                                               const float* __restrict__ kb,
                                               const float* __restrict__ vb,
                                               unsigned short* __restrict__ y) {
    __shared__ float Qs[64][68];
    __shared__ float Ks[64][68];   // reused to hold P after S is consumed
    __shared__ float Vs[64][68];
    const int tid = threadIdx.x;
    const int tx = tid & 15, ty = tid >> 4;
    const int qt = (int)gridDim.x - 1 - (int)blockIdx.x;   // LPT: long blocks first
    const int bh = blockIdx.y;
    const size_t base = (size_t)bh * T_SEQ * HD;
    const int q0 = qt << 6;
    const float NEG_INF = -__builtin_inff();

#pragma unroll
    for (int i = 0; i < 4; i++) {
        int f = (i << 8) + tid;
        int r = f >> 4, c = (f & 15) << 2;
        *(float4*)&Qs[r][c] = *(const float4*)(qb + base + (size_t)(q0 + r) * HD + c);
    }
    float o[4][4] = {};
    float m_prev[4] = {NEG_INF, NEG_INF, NEG_INF, NEG_INF};
    float l_run[4] = {};

    for (int kt = 0; kt <= qt; kt++) {
        const int k0 = kt << 6;
        __syncthreads();
#pragma unroll
        for (int i = 0; i < 4; i++) {
            int f = (i << 8) + tid;
            int r = f >> 4, c = (f & 15) << 2;
            *(float4*)&Ks[r][c] = *(const float4*)(kb + base + (size_t)(k0 + r) * HD + c);
            *(float4*)&Vs[r][c] = *(const float4*)(vb + base + (size_t)(k0 + r) * HD + c);
        }
        __syncthreads();

        // S = Q K^T  (rows ty*4+i, cols tx+16j)
        float s[4][4] = {};
#pragma unroll 4
        for (int d0 = 0; d0 < 64; d0 += 4) {
            float4 q4[4], k4[4];
#pragma unroll
            for (int i = 0; i < 4; i++) q4[i] = *(float4*)&Qs[(ty << 2) + i][d0];
#pragma unroll
            for (int j = 0; j < 4; j++) k4[j] = *(float4*)&Ks[tx + (j << 4)][d0];
#pragma unroll
            for (int i = 0; i < 4; i++)
#pragma unroll
                for (int j = 0; j < 4; j++)
                    s[i][j] += q4[i].x * k4[j].x + q4[i].y * k4[j].y +
                               q4[i].z * k4[j].z + q4[i].w * k4[j].w;
        }

        // mask + scale + online softmax
#pragma unroll
        for (int i = 0; i < 4; i++) {
            int qi = q0 + (ty << 2) + i;
            float mx = NEG_INF;
#pragma unroll
            for (int j = 0; j < 4; j++) {
                int ki = k0 + tx + (j << 4);
                s[i][j] = (ki <= qi) ? s[i][j] * 0.125f : NEG_INF;
                mx = fmaxf(mx, s[i][j]);
            }
#pragma unroll
            for (int off = 8; off; off >>= 1) mx = fmaxf(mx, __shfl_xor(mx, off, 16));
            float m_new = fmaxf(m_prev[i], mx);
            float alpha = __expf(m_prev[i] - m_new);
            float ssum = 0.f;
#pragma unroll
            for (int j = 0; j < 4; j++) { s[i][j] = __expf(s[i][j] - m_new); ssum += s[i][j]; }
#pragma unroll
            for (int off = 8; off; off >>= 1) ssum += __shfl_xor(ssum, off, 16);
            l_run[i] = l_run[i] * alpha + ssum;
            m_prev[i] = m_new;
#pragma unroll
            for (int j = 0; j < 4; j++) o[i][j] *= alpha;
        }

        __syncthreads();                // Ks reads done -> reuse for P
#pragma unroll
        for (int i = 0; i < 4; i++)
#pragma unroll
            for (int j = 0; j < 4; j++)
                Ks[(ty << 2) + i][tx + (j << 4)] = s[i][j];
        __syncthreads();

        // O += P @ V
#pragma unroll 4
        for (int c0 = 0; c0 < 64; c0 += 4) {
            float4 pr[4], vv[4];
#pragma unroll
            for (int i = 0; i < 4; i++) pr[i] = *(float4*)&Ks[(ty << 2) + i][c0];
#pragma unroll
            for (int u = 0; u < 4; u++) vv[u] = *(float4*)&Vs[c0 + u][tx << 2];
#pragma unroll
            for (int i = 0; i < 4; i++) {
                o[i][0] += pr[i].x * vv[0].x + pr[i].y * vv[1].x + pr[i].z * vv[2].x + pr[i].w * vv[3].x;
                o[i][1] += pr[i].x * vv[0].y + pr[i].y * vv[1].y + pr[i].z * vv[2].y + pr[i].w * vv[3].y;
                o[i][2] += pr[i].x * vv[0].z + pr[i].y * vv[1].z + pr[i].z * vv[2].z + pr[i].w * vv[3].z;
                o[i][3] += pr[i].x * vv[0].w + pr[i].y * vv[1].w + pr[i].z * vv[2].w + pr[i].w * vv[3].w;
            }
        }
    }

    // y[b, t, h*64+d] as bf16 (A-matrix of the out-projection)
    const int b = bh >> 4, h = bh & 15;
#pragma unroll
    for (int i = 0; i < 4; i++) {
        float inv = 1.0f / l_run[i];
        int t = q0 + (ty << 2) + i;
        ushort4 o4;
        o4.x = f2bf(o[i][0] * inv);
        o4.y = f2bf(o[i][1] * inv);
        o4.z = f2bf(o[i][2] * inv);
        o4.w = f2bf(o[i][3] * inv);
        *(ushort4*)(y + ((size_t)b * T_SEQ + t) * C_DIM + h * HD + (tx << 2)) = o4;
    }
}

extern "C" void kernel_launch(void* const* d_in, const int* in_sizes, int n_in,
                              void* d_out, int out_size, void* d_ws, size_t ws_size,
                              hipStream_t stream) {
    (void)in_sizes; (void)n_in; (void)out_size; (void)ws_size;
    const float* x     = (const float*)d_in[0];
    const float* w_qkv = (const float*)d_in[1];
    const float* b_qkv = (const float*)d_in[2];
    const float* w_out = (const float*)d_in[3];
    const float* b_out = (const float*)d_in[4];
    float* out = (float*)d_out;

    char* ws = (char*)d_ws;
    float*          qb    = (float*)ws;                              // 16 MB
    float*          kb    = (float*)(ws + ((size_t)16 << 20));       // 16 MB
    float*          vb    = (float*)(ws + ((size_t)32 << 20));       // 16 MB
    unsigned short* xb    = (unsigned short*)(ws + ((size_t)48 << 20)); // 8 MB (aliased with yb)
    unsigned short* yb    = xb;
    unsigned short* wqkvT = (unsigned short*)(ws + ((size_t)56 << 20)); // 6 MB
    unsigned short* woutT = (unsigned short*)(ws + ((size_t)62 << 20)); // 2 MB

    convert_bf16  <<<1024, 256, 0, stream>>>(x, xb, BT * C_DIM);
    transpose_bf16<<<dim3(48, 16), 256, 0, stream>>>(w_qkv, wqkvT, 1024, 3072);
    transpose_bf16<<<dim3(16, 16), 256, 0, stream>>>(w_out, woutT, 1024, 1024);
    gemm_qkv      <<<dim3(24, 32), 256, 0, stream>>>(xb, wqkvT, b_qkv, qb, kb, vb);
    attn          <<<dim3(32, 32), 256, 0, stream>>>(qb, kb, vb, yb);
    gemm_out      <<<dim3(8, 32), 256, 0, stream>>>(yb, woutT, b_out, out);
}

// Round 3
// 272.144 us; speedup vs baseline: 7.0738x; 2.5560x over previous
//
#include <hip/hip_runtime.h>

// B=2, T=2048, C=1024, H=16, hd=64. fp32 in/out; bf16 MFMA everywhere.
// ws (40 MB): qb bf16 8MB | kb bf16 8MB | vt bf16 8MB (transposed [bh][d][t]) |
//             xb/yb bf16 8MB (aliased) | wqkvT bf16 6MB | woutT bf16 2MB

#define T_SEQ 2048
#define C_DIM 1024
#define NH    16
#define HD    64
#define BT    4096

typedef short bf16x8 __attribute__((ext_vector_type(8)));   // 8 bf16 (4 VGPRs)
typedef float floatx4 __attribute__((ext_vector_type(4)));  // MFMA accum

static __device__ __forceinline__ unsigned short f2bf(float f) {
    union { float f; unsigned u; } v; v.f = f;
    unsigned u = v.u;
    return (unsigned short)((u + 0x7FFFu + ((u >> 16) & 1u)) >> 16);
}

// ---------------- fp32 -> bf16 elementwise ----------------
__global__ __launch_bounds__(256) void convert_bf16(const float* __restrict__ in,
                                                    unsigned short* __restrict__ out, int n) {
    int i = (blockIdx.x * 256 + threadIdx.x) * 4;
    const int stride = gridDim.x * 1024;
    for (; i < n; i += stride) {
        float4 f = *(const float4*)(in + i);
        ushort4 o;
        o.x = f2bf(f.x); o.y = f2bf(f.y); o.z = f2bf(f.z); o.w = f2bf(f.w);
        *(ushort4*)(out + i) = o;
    }
}

// ---------------- fp32 [K][N] -> bf16 [N][K] (W^T) ----------------
__global__ __launch_bounds__(256) void transpose_bf16(const float* __restrict__ W,
                                                      unsigned short* __restrict__ Wt,
                                                      int K, int N) {
    __shared__ float tile[64][65];
    const int k0 = blockIdx.y << 6;
    const int n0 = blockIdx.x << 6;
    const int rr = threadIdx.x >> 4;
    const int cc = (threadIdx.x & 15) << 2;
#pragma unroll
    for (int i = 0; i < 4; i++) {
        int r = rr + (i << 4);
        *(float4*)&tile[r][cc] = *(const float4*)(W + (size_t)(k0 + r) * N + n0 + cc);
    }
    __syncthreads();
#pragma unroll
    for (int i = 0; i < 4; i++) {
        int nr = rr + (i << 4);
        ushort4 o;
        o.x = f2bf(tile[cc + 0][nr]);
        o.y = f2bf(tile[cc + 1][nr]);
        o.z = f2bf(tile[cc + 2][nr]);
        o.w = f2bf(tile[cc + 3][nr]);
        *(ushort4*)(Wt + (size_t)(n0 + nr) * K + k0 + cc) = o;
    }
}

// ---------------- bf16 MFMA GEMM: qkv = X @ Wt^T + bias -> bf16 q/k/vT -----
// q scaled by 0.125 (exact) so attn S needs no scale multiply.
__global__ __launch_bounds__(256) void gemm_qkv(const unsigned short* __restrict__ A,
                                                const unsigned short* __restrict__ Bt,
                                                const float* __restrict__ bias,
                                                unsigned short* __restrict__ qb,
                                                unsigned short* __restrict__ kb,
                                                unsigned short* __restrict__ vt) {
    const int K = 1024;
    __shared__ short As[128][40];
    __shared__ short Bs[128][40];
    const int tid  = threadIdx.x;
    const int lane = tid & 63, wave = tid >> 6;
    const int ln   = lane & 15, quad = lane >> 4;
    const int wm   = wave & 1,  wn   = wave >> 1;
    const int row0 = blockIdx.y << 7;
    const int col0 = blockIdx.x << 7;
    floatx4 acc[4][4];
#pragma unroll
    for (int i = 0; i < 4; i++)
#pragma unroll
        for (int j = 0; j < 4; j++) acc[i][j] = (floatx4){0.f, 0.f, 0.f, 0.f};

    for (int k0 = 0; k0 < K; k0 += 32) {
#pragma unroll
        for (int cc = 0; cc < 2; cc++) {
            int c = (cc << 8) + tid;
            int r = c >> 2, q = c & 3;
            *(bf16x8*)&As[r][q << 3] = *(const bf16x8*)(A  + (size_t)(row0 + r) * K + k0 + (q << 3));
            *(bf16x8*)&Bs[r][q << 3] = *(const bf16x8*)(Bt + (size_t)(col0 + r) * K + k0 + (q << 3));
        }
        __syncthreads();
        bf16x8 af[4], bfr[4];
#pragma unroll
        for (int t = 0; t < 4; t++) af[t]  = *(bf16x8*)&As[(wm << 6) + (t << 4) + ln][quad << 3];
#pragma unroll
        for (int t = 0; t < 4; t++) bfr[t] = *(bf16x8*)&Bs[(wn << 6) + (t << 4) + ln][quad << 3];
#pragma unroll
        for (int mt = 0; mt < 4; mt++)
#pragma unroll
            for (int nt = 0; nt < 4; nt++)
                acc[mt][nt] = __builtin_amdgcn_mfma_f32_16x16x32_bf16(af[mt], bfr[nt], acc[mt][nt], 0, 0, 0);
        __syncthreads();
    }
    // epilogue: +bias, q*=0.125, scatter to bf16 q/k/vT
#pragma unroll
    for (int mt = 0; mt < 4; mt++) {
#pragma unroll
        for (int nt = 0; nt < 4; nt++) {
            int n = col0 + (wn << 6) + (nt << 4) + ln;
            int h = n / 192, r = n % 192;
            int sel = r >> 6, d = r & 63;
            float bv = bias[n];
#pragma unroll
            for (int e = 0; e < 4; e++) {
                int m = row0 + (wm << 6) + (mt << 4) + (quad << 2) + e;
                int b = m >> 11, t = m & 2047;
                float val = acc[mt][nt][e] + bv;
                int bh = b * NH + h;
                if (sel == 0)
                    qb[((size_t)bh * T_SEQ + t) * HD + d] = f2bf(val * 0.125f);
                else if (sel == 1)
                    kb[((size_t)bh * T_SEQ + t) * HD + d] = f2bf(val);
                else
                    vt[((size_t)bh * HD + d) * T_SEQ + t] = f2bf(val);
            }
        }
    }
}

// ---------------- bf16 MFMA GEMM: out = Y @ WoutT^T + bias (fp32 out) -------
__global__ __launch_bounds__(256) void gemm_out(const unsigned short* __restrict__ A,
                                                const unsigned short* __restrict__ Bt,
                                                const float* __restrict__ bias,
                                                float* __restrict__ out) {
    const int K = 1024, N = 1024;
    __shared__ short As[128][40];
    __shared__ short Bs[128][40];
    const int tid  = threadIdx.x;
    const int lane = tid & 63, wave = tid >> 6;
    const int ln   = lane & 15, quad = lane >> 4;
    const int wm   = wave & 1,  wn   = wave >> 1;
    const int row0 = blockIdx.y << 7;
    const int col0 = blockIdx.x << 7;
    floatx4 acc[4][4];
#pragma unroll
    for (int i = 0; i < 4; i++)
#pragma unroll
        for (int j = 0; j < 4; j++) acc[i][j] = (floatx4){0.f, 0.f, 0.f, 0.f};

    for (int k0 = 0; k0 < K; k0 += 32) {
#pragma unroll
        for (int cc = 0; cc < 2; cc++) {
            int c = (cc << 8) + tid;
            int r = c >> 2, q = c & 3;
            *(bf16x8*)&As[r][q << 3] = *(const bf16x8*)(A  + (size_t)(row0 + r) * K + k0 + (q << 3));
            *(bf16x8*)&Bs[r][q << 3] = *(const bf16x8*)(Bt + (size_t)(col0 + r) * K + k0 + (q << 3));
        }
        __syncthreads();
        bf16x8 af[4], bfr[4];
#pragma unroll
        for (int t = 0; t < 4; t++) af[t]  = *(bf16x8*)&As[(wm << 6) + (t << 4) + ln][quad << 3];
#pragma unroll
        for (int t = 0; t < 4; t++) bfr[t] = *(bf16x8*)&Bs[(wn << 6) + (t << 4) + ln][quad << 3];
#pragma unroll
        for (int mt = 0; mt < 4; mt++)
#pragma unroll
            for (int nt = 0; nt < 4; nt++)
                acc[mt][nt] = __builtin_amdgcn_mfma_f32_16x16x32_bf16(af[mt], bfr[nt], acc[mt][nt], 0, 0, 0);
        __syncthreads();
    }
#pragma unroll
    for (int mt = 0; mt < 4; mt++) {
#pragma unroll
        for (int nt = 0; nt < 4; nt++) {
            int n = col0 + (wn << 6) + (nt << 4) + ln;
            float bv = bias[n];
#pragma unroll
            for (int e = 0; e < 4; e++) {
                int m = row0 + (wm << 6) + (mt << 4) + (quad << 2) + e;
                out[(size_t)m * N + n] = acc[mt][nt][e] + bv;
            }
        }
    }
}

// ---------------- MFMA flash attention ----------------
// grid (32 qtiles, 32 bh), 4 waves. Wave w owns S/O rows [16w,16w+16).
// S strip: A=Qs[16w+ln][quad*8..], B=Ks[nt*16+ln][quad*8..]; C row=quad*4+e,col=ln.
// P round-trips wave-private through Ps (no barrier). V pre-transposed: Vs[d][kpos]
// is NOT needed -- B-operand of PV reads Vs[nt*16+ln][quad*8..] from Vt[d][kpos].
__global__ __launch_bounds__(256, 3) void attn(const unsigned short* __restrict__ qb,
                                               const unsigned short* __restrict__ kb,
                                               const unsigned short* __restrict__ vt,
                                               unsigned short* __restrict__ y) {
    __shared__ short Qs[64][72];
    __shared__ short Ks[64][72];
    __shared__ short Vs[64][72];   // Vs[d][kpos]
    __shared__ short Ps[64][72];
    const int tid  = threadIdx.x;
    const int wave = tid >> 6, lane = tid & 63;
    const int ln   = lane & 15, quad = lane >> 4;
    const int qt = (int)gridDim.x - 1 - (int)blockIdx.x;   // LPT: long blocks first
    const int bh = blockIdx.y;
    const size_t base = (size_t)bh * T_SEQ * HD;
    const int q0 = qt << 6;
    const float NEG_INF = -__builtin_inff();

#pragma unroll
    for (int i = 0; i < 2; i++) {                 // Q tile 64x64 bf16
        int idx = (i << 8) + tid;
        int r = idx >> 3, c = (idx & 7) << 3;
        *(bf16x8*)&Qs[r][c] = *(const bf16x8*)(qb + base + (size_t)(q0 + r) * HD + c);
    }
    floatx4 o[4];
#pragma unroll
    for (int nt = 0; nt < 4; nt++) o[nt] = (floatx4){0.f, 0.f, 0.f, 0.f};
    float m_prev[4] = {NEG_INF, NEG_INF, NEG_INF, NEG_INF};
    float l_run[4] = {};

    for (int kt = 0; kt <= qt; kt++) {
        const int k0 = kt << 6;
        __syncthreads();   // prior-iter Ks/Vs reads done (covers Qs write for kt=0)
#pragma unroll
        for (int i = 0; i < 2; i++) {
            int idx = (i << 8) + tid;
            int r = idx >> 3, c = (idx & 7) << 3;
            *(bf16x8*)&Ks[r][c] = *(const bf16x8*)(kb + base + (size_t)(k0 + r) * HD + c);
            *(bf16x8*)&Vs[r][c] = *(const bf16x8*)(vt + base + (size_t)r * T_SEQ + k0 + c);
        }
        __syncthreads();

        // S strip = Q K^T  (8 MFMAs)
        bf16x8 aq0 = *(bf16x8*)&Qs[(wave << 4) + ln][quad << 3];
        bf16x8 aq1 = *(bf16x8*)&Qs[(wave << 4) + ln][32 + (quad << 3)];
        floatx4 s[4];
#pragma unroll
        for (int nt = 0; nt < 4; nt++) {
            bf16x8 b0 = *(bf16x8*)&Ks[(nt << 4) + ln][quad << 3];
            bf16x8 b1 = *(bf16x8*)&Ks[(nt << 4) + ln][32 + (quad << 3)];
            floatx4 acc = (floatx4){0.f, 0.f, 0.f, 0.f};
            acc = __builtin_amdgcn_mfma_f32_16x16x32_bf16(aq0, b0, acc, 0, 0, 0);
            acc = __builtin_amdgcn_mfma_f32_16x16x32_bf16(aq1, b1, acc, 0, 0, 0);
            s[nt] = acc;
        }

        // causal mask only on the diagonal tile (wave-uniform branch)
        if (kt == qt) {
#pragma unroll
            for (int nt = 0; nt < 4; nt++) {
                int kcol = (nt << 4) + ln;
#pragma unroll
                for (int e = 0; e < 4; e++) {
                    int qrow = (wave << 4) + (quad << 2) + e;
                    if (kcol > qrow) s[nt][e] = NEG_INF;
                }
            }
        }

        // online softmax per row (row = quad*4+e; 16-lane segment reduction)
#pragma unroll
        for (int e = 0; e < 4; e++) {
            float mx = fmaxf(fmaxf(s[0][e], s[1][e]), fmaxf(s[2][e], s[3][e]));
#pragma unroll
            for (int off = 8; off; off >>= 1) mx = fmaxf(mx, __shfl_xor(mx, off));
            float m_new = fmaxf(m_prev[e], mx);
            float alpha = __expf(m_prev[e] - m_new);
            float ssum = 0.f;
#pragma unroll
            for (int nt = 0; nt < 4; nt++) {
                float p = __expf(s[nt][e] - m_new);
                s[nt][e] = p;
                ssum += p;
            }
#pragma unroll
            for (int off = 8; off; off >>= 1) ssum += __shfl_xor(ssum, off);
            l_run[e] = l_run[e] * alpha + ssum;
            m_prev[e] = m_new;
#pragma unroll
            for (int nt = 0; nt < 4; nt++) o[nt][e] *= alpha;
        }

        // P strip -> LDS (bf16), wave-private rows [16w,16w+16)
#pragma unroll
        for (int nt = 0; nt < 4; nt++)
#pragma unroll
            for (int e = 0; e < 4; e++)
                Ps[(wave << 4) + (quad << 2) + e][(nt << 4) + ln] = f2bf(s[nt][e]);

        // O strip += P @ V  (8 MFMAs; reads only rows this wave wrote)
        bf16x8 ap0 = *(bf16x8*)&Ps[(wave << 4) + ln][quad << 3];
        bf16x8 ap1 = *(bf16x8*)&Ps[(wave << 4) + ln][32 + (quad << 3)];
#pragma unroll
        for (int nt = 0; nt < 4; nt++) {
            bf16x8 v0 = *(bf16x8*)&Vs[(nt << 4) + ln][quad << 3];
            bf16x8 v1 = *(bf16x8*)&Vs[(nt << 4) + ln][32 + (quad << 3)];
            o[nt] = __builtin_amdgcn_mfma_f32_16x16x32_bf16(ap0, v0, o[nt], 0, 0, 0);
            o[nt] = __builtin_amdgcn_mfma_f32_16x16x32_bf16(ap1, v1, o[nt], 0, 0, 0);
        }
    }

    // y[b, t, h*64+d] bf16 (A-matrix of out-projection)
    const int b = bh >> 4, h = bh & 15;
#pragma unroll
    for (int e = 0; e < 4; e++) {
        float inv = 1.0f / l_run[e];
        int t = q0 + (wave << 4) + (quad << 2) + e;
        unsigned short* yrow = y + ((size_t)b * T_SEQ + t) * C_DIM + h * HD;
#pragma unroll
        for (int nt = 0; nt < 4; nt++)
            yrow[(nt << 4) + ln] = f2bf(o[nt][e] * inv);
    }
}

extern "C" void kernel_launch(void* const* d_in, const int* in_sizes, int n_in,
                              void* d_out, int out_size, void* d_ws, size_t ws_size,
                              hipStream_t stream) {
    (void)in_sizes; (void)n_in; (void)out_size; (void)ws_size;
    const float* x     = (const float*)d_in[0];
    const float* w_qkv = (const float*)d_in[1];
    const float* b_qkv = (const float*)d_in[2];
    const float* w_out = (const float*)d_in[3];
    const float* b_out = (const float*)d_in[4];
    float* out = (float*)d_out;

    char* ws = (char*)d_ws;
    unsigned short* qb    = (unsigned short*)ws;                        // 8 MB
    unsigned short* kb    = (unsigned short*)(ws + ((size_t)8  << 20)); // 8 MB
    unsigned short* vt    = (unsigned short*)(ws + ((size_t)16 << 20)); // 8 MB
    unsigned short* xb    = (unsigned short*)(ws + ((size_t)24 << 20)); // 8 MB (alias yb)
    unsigned short* yb    = xb;
    unsigned short* wqkvT = (unsigned short*)(ws + ((size_t)32 << 20)); // 6 MB
    unsigned short* woutT = (unsigned short*)(ws + ((size_t)38 << 20)); // 2 MB

    convert_bf16  <<<1024, 256, 0, stream>>>(x, xb, BT * C_DIM);
    transpose_bf16<<<dim3(48, 16), 256, 0, stream>>>(w_qkv, wqkvT, 1024, 3072);
    transpose_bf16<<<dim3(16, 16), 256, 0, stream>>>(w_out, woutT, 1024, 1024);
    gemm_qkv      <<<dim3(24, 32), 256, 0, stream>>>(xb, wqkvT, b_qkv, qb, kb, vt);
    attn          <<<dim3(32, 32), 256, 0, stream>>>(qb, kb, vt, yb);
    gemm_out      <<<dim3(8, 32), 256, 0, stream>>>(yb, woutT, b_out, out);
}

// Round 4
// 270.743 us; speedup vs baseline: 7.1104x; 1.0052x over previous
//
#include <hip/hip_runtime.h>

// B=2, T=2048, C=1024, H=16, hd=64. fp32 in/out; bf16 MFMA everywhere.
// ws (40 MB): qb bf16 8MB | kb bf16 8MB | vt bf16 8MB ([bh][d][t]) |
//             xb/yb bf16 8MB (aliased) | wqkvT bf16 6MB | woutT bf16 2MB

#define T_SEQ 2048
#define C_DIM 1024
#define NH    16
#define HD    64
#define BT    4096

typedef short bf16x8 __attribute__((ext_vector_type(8)));   // 8 bf16 (4 VGPRs)
typedef float floatx4 __attribute__((ext_vector_type(4)));  // MFMA accum

static __device__ __forceinline__ unsigned short f2bf(float f) {
    union { float f; unsigned u; } v; v.f = f;
    unsigned u = v.u;
    return (unsigned short)((u + 0x7FFFu + ((u >> 16) & 1u)) >> 16);
}

// ---------------- fp32 -> bf16 elementwise ----------------
__global__ __launch_bounds__(256) void convert_bf16(const float* __restrict__ in,
                                                    unsigned short* __restrict__ out, int n) {
    int i = (blockIdx.x * 256 + threadIdx.x) * 4;
    const int stride = gridDim.x * 1024;
    for (; i < n; i += stride) {
        float4 f = *(const float4*)(in + i);
        ushort4 o;
        o.x = f2bf(f.x); o.y = f2bf(f.y); o.z = f2bf(f.z); o.w = f2bf(f.w);
        *(ushort4*)(out + i) = o;
    }
}

// ---------------- fp32 [K][N] -> bf16 [N][K] (W^T) ----------------
__global__ __launch_bounds__(256) void transpose_bf16(const float* __restrict__ W,
                                                      unsigned short* __restrict__ Wt,
                                                      int K, int N) {
    __shared__ float tile[64][65];
    const int k0 = blockIdx.y << 6;
    const int n0 = blockIdx.x << 6;
    const int rr = threadIdx.x >> 4;
    const int cc = (threadIdx.x & 15) << 2;
#pragma unroll
    for (int i = 0; i < 4; i++) {
        int r = rr + (i << 4);
        *(float4*)&tile[r][cc] = *(const float4*)(W + (size_t)(k0 + r) * N + n0 + cc);
    }
    __syncthreads();
#pragma unroll
    for (int i = 0; i < 4; i++) {
        int nr = rr + (i << 4);
        ushort4 o;
        o.x = f2bf(tile[cc + 0][nr]);
        o.y = f2bf(tile[cc + 1][nr]);
        o.z = f2bf(tile[cc + 2][nr]);
        o.w = f2bf(tile[cc + 3][nr]);
        *(ushort4*)(Wt + (size_t)(n0 + nr) * K + k0 + cc) = o;
    }
}

// ---------------- bf16 MFMA GEMM: qkv = X @ Wt^T + bias -> bf16 q/k/vT -----
__global__ __launch_bounds__(256) void gemm_qkv(const unsigned short* __restrict__ A,
                                                const unsigned short* __restrict__ Bt,
                                                const float* __restrict__ bias,
                                                unsigned short* __restrict__ qb,
                                                unsigned short* __restrict__ kb,
                                                unsigned short* __restrict__ vt) {
    const int K = 1024;
    __shared__ short As[128][40];
    __shared__ short Bs[128][40];
    const int tid  = threadIdx.x;
    const int lane = tid & 63, wave = tid >> 6;
    const int ln   = lane & 15, quad = lane >> 4;
    const int wm   = wave & 1,  wn   = wave >> 1;
    const int row0 = blockIdx.y << 7;
    const int col0 = blockIdx.x << 7;
    floatx4 acc[4][4];
#pragma unroll
    for (int i = 0; i < 4; i++)
#pragma unroll
        for (int j = 0; j < 4; j++) acc[i][j] = (floatx4){0.f, 0.f, 0.f, 0.f};

    for (int k0 = 0; k0 < K; k0 += 32) {
#pragma unroll
        for (int cc = 0; cc < 2; cc++) {
            int c = (cc << 8) + tid;
            int r = c >> 2, q = c & 3;
            *(bf16x8*)&As[r][q << 3] = *(const bf16x8*)(A  + (size_t)(row0 + r) * K + k0 + (q << 3));
            *(bf16x8*)&Bs[r][q << 3] = *(const bf16x8*)(Bt + (size_t)(col0 + r) * K + k0 + (q << 3));
        }
        __syncthreads();
        bf16x8 af[4], bfr[4];
#pragma unroll
        for (int t = 0; t < 4; t++) af[t]  = *(bf16x8*)&As[(wm << 6) + (t << 4) + ln][quad << 3];
#pragma unroll
        for (int t = 0; t < 4; t++) bfr[t] = *(bf16x8*)&Bs[(wn << 6) + (t << 4) + ln][quad << 3];
#pragma unroll
        for (int mt = 0; mt < 4; mt++)
#pragma unroll
            for (int nt = 0; nt < 4; nt++)
                acc[mt][nt] = __builtin_amdgcn_mfma_f32_16x16x32_bf16(af[mt], bfr[nt], acc[mt][nt], 0, 0, 0);
        __syncthreads();
    }
#pragma unroll
    for (int mt = 0; mt < 4; mt++) {
#pragma unroll
        for (int nt = 0; nt < 4; nt++) {
            int n = col0 + (wn << 6) + (nt << 4) + ln;
            int h = n / 192, r = n % 192;
            int sel = r >> 6, d = r & 63;
            float bv = bias[n];
#pragma unroll
            for (int e = 0; e < 4; e++) {
                int m = row0 + (wm << 6) + (mt << 4) + (quad << 2) + e;
                int b = m >> 11, t = m & 2047;
                float val = acc[mt][nt][e] + bv;
                int bh = b * NH + h;
                if (sel == 0)
                    qb[((size_t)bh * T_SEQ + t) * HD + d] = f2bf(val * 0.125f);
                else if (sel == 1)
                    kb[((size_t)bh * T_SEQ + t) * HD + d] = f2bf(val);
                else
                    vt[((size_t)bh * HD + d) * T_SEQ + t] = f2bf(val);
            }
        }
    }
}

// ---------------- bf16 MFMA GEMM: out = Y @ WoutT^T + bias (fp32 out) -------
__global__ __launch_bounds__(256) void gemm_out(const unsigned short* __restrict__ A,
                                                const unsigned short* __restrict__ Bt,
                                                const float* __restrict__ bias,
                                                float* __restrict__ out) {
    const int K = 1024, N = 1024;
    __shared__ short As[128][40];
    __shared__ short Bs[128][40];
    const int tid  = threadIdx.x;
    const int lane = tid & 63, wave = tid >> 6;
    const int ln   = lane & 15, quad = lane >> 4;
    const int wm   = wave & 1,  wn   = wave >> 1;
    const int row0 = blockIdx.y << 7;
    const int col0 = blockIdx.x << 7;
    floatx4 acc[4][4];
#pragma unroll
    for (int i = 0; i < 4; i++)
#pragma unroll
        for (int j = 0; j < 4; j++) acc[i][j] = (floatx4){0.f, 0.f, 0.f, 0.f};

    for (int k0 = 0; k0 < K; k0 += 32) {
#pragma unroll
        for (int cc = 0; cc < 2; cc++) {
            int c = (cc << 8) + tid;
            int r = c >> 2, q = c & 3;
            *(bf16x8*)&As[r][q << 3] = *(const bf16x8*)(A  + (size_t)(row0 + r) * K + k0 + (q << 3));
            *(bf16x8*)&Bs[r][q << 3] = *(const bf16x8*)(Bt + (size_t)(col0 + r) * K + k0 + (q << 3));
        }
        __syncthreads();
        bf16x8 af[4], bfr[4];
#pragma unroll
        for (int t = 0; t < 4; t++) af[t]  = *(bf16x8*)&As[(wm << 6) + (t << 4) + ln][quad << 3];
#pragma unroll
        for (int t = 0; t < 4; t++) bfr[t] = *(bf16x8*)&Bs[(wn << 6) + (t << 4) + ln][quad << 3];
#pragma unroll
        for (int mt = 0; mt < 4; mt++)
#pragma unroll
            for (int nt = 0; nt < 4; nt++)
                acc[mt][nt] = __builtin_amdgcn_mfma_f32_16x16x32_bf16(af[mt], bfr[nt], acc[mt][nt], 0, 0, 0);
        __syncthreads();
    }
#pragma unroll
    for (int mt = 0; mt < 4; mt++) {
#pragma unroll
        for (int nt = 0; nt < 4; nt++) {
            int n = col0 + (wn << 6) + (nt << 4) + ln;
            float bv = bias[n];
#pragma unroll
            for (int e = 0; e < 4; e++) {
                int m = row0 + (wm << 6) + (mt << 4) + (quad << 2) + e;
                out[(size_t)m * N + n] = acc[mt][nt][e] + bv;
            }
        }
    }
}

// ---------------- MFMA flash attention v3 ----------------
// Q-tile 128, K-tile 64, 4 waves; wave w owns strips rows {16w..} and {64+16w..}.
// K/V frag reads feed both strips (2x reuse). Q-frags hoisted pre-loop; Qs LDS
// reused as Ps. K/V staged via register double-buffer (loads fly behind compute).
__global__ __launch_bounds__(256, 3) void attn(const unsigned short* __restrict__ qb,
                                               const unsigned short* __restrict__ kb,
                                               const unsigned short* __restrict__ vt,
                                               unsigned short* __restrict__ y) {
    __shared__ short Ks[64][72];    // [k-row][d]
    __shared__ short Vs[64][72];    // [d][k-col]  (from vt)
    __shared__ short QP[128][72];   // Qs pre-loop, then Ps
    const int tid  = threadIdx.x;
    const int w    = tid >> 6, lane = tid & 63;
    const int ln   = lane & 15, quad = lane >> 4;
    const int qt   = 15 - (int)blockIdx.x;          // LPT: long blocks first
    const int bh   = blockIdx.y;
    const size_t base = (size_t)bh * T_SEQ * HD;
    const int q0   = qt << 7;
    const int ktmax = 2 * qt + 1;
    const float NEG_INF = -__builtin_inff();

    const int sr = tid >> 3;          // staging row (0..31, +32*i)
    const int sc = (tid & 7) << 3;    // staging col (bf16x8)

    // stage Q + prefetch K/V tile 0
    bf16x8 qtmp[4];
#pragma unroll
    for (int i = 0; i < 4; i++)
        qtmp[i] = *(const bf16x8*)(qb + base + (size_t)(q0 + sr + (i << 5)) * HD + sc);
    bf16x8 kreg[2], vreg[2];
#pragma unroll
    for (int i = 0; i < 2; i++) {
        kreg[i] = *(const bf16x8*)(kb + base + (size_t)(sr + (i << 5)) * HD + sc);
        vreg[i] = *(const bf16x8*)(vt + base + (size_t)(sr + (i << 5)) * T_SEQ + sc);
    }
#pragma unroll
    for (int i = 0; i < 4; i++) *(bf16x8*)&QP[sr + (i << 5)][sc] = qtmp[i];
    __syncthreads();

    // hoist loop-invariant Q fragments (each wave reads only its own rows,
    // which are exactly the Ps rows it will later write -> wave-local ordering ok)
    bf16x8 aq[2][2];
    aq[0][0] = *(bf16x8*)&QP[(w << 4) + ln][quad << 3];
    aq[0][1] = *(bf16x8*)&QP[(w << 4) + ln][32 + (quad << 3)];
    aq[1][0] = *(bf16x8*)&QP[64 + (w << 4) + ln][quad << 3];
    aq[1][1] = *(bf16x8*)&QP[64 + (w << 4) + ln][32 + (quad << 3)];

    floatx4 o[2][4];
#pragma unroll
    for (int s = 0; s < 2; s++)
#pragma unroll
        for (int nt = 0; nt < 4; nt++) o[s][nt] = (floatx4){0.f, 0.f, 0.f, 0.f};
    float m_prev[2][4], l_run[2][4];
#pragma unroll
    for (int s = 0; s < 2; s++)
#pragma unroll
        for (int e = 0; e < 4; e++) { m_prev[s][e] = NEG_INF; l_run[s][e] = 0.f; }

    const int sb[2] = {q0 + (w << 4), q0 + 64 + (w << 4)};

    for (int kt = 0; kt <= ktmax; kt++) {
        const int k0 = kt << 6;
        __syncthreads();                       // prev-iter LDS reads done
#pragma unroll
        for (int i = 0; i < 2; i++) {
            *(bf16x8*)&Ks[sr + (i << 5)][sc] = kreg[i];
            *(bf16x8*)&Vs[sr + (i << 5)][sc] = vreg[i];
        }
        __syncthreads();
        if (kt < ktmax) {                      // prefetch next tile behind compute
            const int kn = k0 + 64;
#pragma unroll
            for (int i = 0; i < 2; i++) {
                kreg[i] = *(const bf16x8*)(kb + base + (size_t)(kn + sr + (i << 5)) * HD + sc);
                vreg[i] = *(const bf16x8*)(vt + base + (size_t)(sr + (i << 5)) * T_SEQ + kn + sc);
            }
        }

        const bool live0 = (k0 <= sb[0] + 15); // strip1 always live
        // S for both strips, sharing K-frags
        floatx4 sa[2][4];
#pragma unroll
        for (int nt = 0; nt < 4; nt++) {
            bf16x8 b0 = *(bf16x8*)&Ks[(nt << 4) + ln][quad << 3];
            bf16x8 b1 = *(bf16x8*)&Ks[(nt << 4) + ln][32 + (quad << 3)];
            if (live0) {
                floatx4 a = (floatx4){0.f, 0.f, 0.f, 0.f};
                a = __builtin_amdgcn_mfma_f32_16x16x32_bf16(aq[0][0], b0, a, 0, 0, 0);
                a = __builtin_amdgcn_mfma_f32_16x16x32_bf16(aq[0][1], b1, a, 0, 0, 0);
                sa[0][nt] = a;
            }
            floatx4 c = (floatx4){0.f, 0.f, 0.f, 0.f};
            c = __builtin_amdgcn_mfma_f32_16x16x32_bf16(aq[1][0], b0, c, 0, 0, 0);
            c = __builtin_amdgcn_mfma_f32_16x16x32_bf16(aq[1][1], b1, c, 0, 0, 0);
            sa[1][nt] = c;
        }

        // softmax + P write per strip
#pragma unroll
        for (int s = 0; s < 2; s++) {
            if (s == 0 && !live0) continue;
            const bool needMask = (k0 + 63 > sb[s]);
            if (needMask) {
#pragma unroll
                for (int nt = 0; nt < 4; nt++) {
                    int kcol = k0 + (nt << 4) + ln;
#pragma unroll
                    for (int e = 0; e < 4; e++) {
                        int qrow = sb[s] + (quad << 2) + e;
                        if (kcol > qrow) sa[s][nt][e] = NEG_INF;
                    }
                }
            }
#pragma unroll
            for (int e = 0; e < 4; e++) {
                float mx = fmaxf(fmaxf(sa[s][0][e], sa[s][1][e]), fmaxf(sa[s][2][e], sa[s][3][e]));
#pragma unroll
                for (int off = 8; off; off >>= 1) mx = fmaxf(mx, __shfl_xor(mx, off));
                float m_new = fmaxf(m_prev[s][e], mx);
                float alpha = __expf(m_prev[s][e] - m_new);
                float ssum = 0.f;
#pragma unroll
                for (int nt = 0; nt < 4; nt++) {
                    float p = __expf(sa[s][nt][e] - m_new);
                    sa[s][nt][e] = p;
                    ssum += p;
                }
#pragma unroll
                for (int off = 8; off; off >>= 1) ssum += __shfl_xor(ssum, off);
                l_run[s][e] = l_run[s][e] * alpha + ssum;
                m_prev[s][e] = m_new;
#pragma unroll
                for (int nt = 0; nt < 4; nt++) o[s][nt][e] *= alpha;
            }
            // P -> Ps (wave-private rows)
            const int pr = (s << 6) + (w << 4) + (quad << 2);
#pragma unroll
            for (int nt = 0; nt < 4; nt++)
#pragma unroll
                for (int e = 0; e < 4; e++)
                    QP[pr + e][(nt << 4) + ln] = f2bf(sa[s][nt][e]);
        }

        // joint PV, sharing V-frags across strips
        bf16x8 ap[2][2];
        if (live0) {
            ap[0][0] = *(bf16x8*)&QP[(w << 4) + ln][quad << 3];
            ap[0][1] = *(bf16x8*)&QP[(w << 4) + ln][32 + (quad << 3)];
        }
        ap[1][0] = *(bf16x8*)&QP[64 + (w << 4) + ln][quad << 3];
        ap[1][1] = *(bf16x8*)&QP[64 + (w << 4) + ln][32 + (quad << 3)];
#pragma unroll
        for (int ntd = 0; ntd < 4; ntd++) {
            bf16x8 v0 = *(bf16x8*)&Vs[(ntd << 4) + ln][quad << 3];
            bf16x8 v1 = *(bf16x8*)&Vs[(ntd << 4) + ln][32 + (quad << 3)];
            if (live0) {
                o[0][ntd] = __builtin_amdgcn_mfma_f32_16x16x32_bf16(ap[0][0], v0, o[0][ntd], 0, 0, 0);
                o[0][ntd] = __builtin_amdgcn_mfma_f32_16x16x32_bf16(ap[0][1], v1, o[0][ntd], 0, 0, 0);
            }
            o[1][ntd] = __builtin_amdgcn_mfma_f32_16x16x32_bf16(ap[1][0], v0, o[1][ntd], 0, 0, 0);
            o[1][ntd] = __builtin_amdgcn_mfma_f32_16x16x32_bf16(ap[1][1], v1, o[1][ntd], 0, 0, 0);
        }
    }

    // epilogue: y[b, t, h*64+dv] bf16
    const int b = bh >> 4, h = bh & 15;
#pragma unroll
    for (int s = 0; s < 2; s++) {
#pragma unroll
        for (int e = 0; e < 4; e++) {
            float inv = 1.0f / l_run[s][e];
            int t = sb[s] + (quad << 2) + e;
            unsigned short* yrow = y + ((size_t)b * T_SEQ + t) * C_DIM + h * HD;
#pragma unroll
            for (int ntd = 0; ntd < 4; ntd++)
                yrow[(ntd << 4) + ln] = f2bf(o[s][ntd][e] * inv);
        }
    }
}

extern "C" void kernel_launch(void* const* d_in, const int* in_sizes, int n_in,
                              void* d_out, int out_size, void* d_ws, size_t ws_size,
                              hipStream_t stream) {
    (void)in_sizes; (void)n_in; (void)out_size; (void)ws_size;
    const float* x     = (const float*)d_in[0];
    const float* w_qkv = (const float*)d_in[1];
    const float* b_qkv = (const float*)d_in[2];
    const float* w_out = (const float*)d_in[3];
    const float* b_out = (const float*)d_in[4];
    float* out = (float*)d_out;

    char* ws = (char*)d_ws;
    unsigned short* qb    = (unsigned short*)ws;                        // 8 MB
    unsigned short* kb    = (unsigned short*)(ws + ((size_t)8  << 20)); // 8 MB
    unsigned short* vt    = (unsigned short*)(ws + ((size_t)16 << 20)); // 8 MB
    unsigned short* xb    = (unsigned short*)(ws + ((size_t)24 << 20)); // 8 MB (alias yb)
    unsigned short* yb    = xb;
    unsigned short* wqkvT = (unsigned short*)(ws + ((size_t)32 << 20)); // 6 MB
    unsigned short* woutT = (unsigned short*)(ws + ((size_t)38 << 20)); // 2 MB

    convert_bf16  <<<1024, 256, 0, stream>>>(x, xb, BT * C_DIM);
    transpose_bf16<<<dim3(48, 16), 256, 0, stream>>>(w_qkv, wqkvT, 1024, 3072);
    transpose_bf16<<<dim3(16, 16), 256, 0, stream>>>(w_out, woutT, 1024, 1024);
    gemm_qkv      <<<dim3(24, 32), 256, 0, stream>>>(xb, wqkvT, b_qkv, qb, kb, vt);
    attn          <<<dim3(16, 32), 256, 0, stream>>>(qb, kb, vt, yb);
    gemm_out      <<<dim3(8, 32), 256, 0, stream>>>(yb, woutT, b_out, out);
}

// Round 5
// 231.161 us; speedup vs baseline: 8.3279x; 1.1712x over previous
//
#include <hip/hip_runtime.h>

// B=2, T=2048, C=1024, H=16, hd=64. fp32 in/out; bf16 MFMA everywhere.
// ws (40 MB): qb bf16 8MB | kb bf16 8MB | vt bf16 8MB ([bh][d][t]) |
//             xb/yb bf16 8MB (aliased) | wqkvT bf16 6MB | woutT bf16 2MB

#define T_SEQ 2048
#define C_DIM 1024
#define NH    16
#define HD    64
#define BT    4096

typedef short bf16x8 __attribute__((ext_vector_type(8)));   // 8 bf16 (4 VGPRs)
typedef float floatx4 __attribute__((ext_vector_type(4)));  // MFMA accum

static __device__ __forceinline__ unsigned short f2bf(float f) {
    union { float f; unsigned u; } v; v.f = f;
    unsigned u = v.u;
    return (unsigned short)((u + 0x7FFFu + ((u >> 16) & 1u)) >> 16);
}

// ---------------- fp32 -> bf16 elementwise ----------------
__global__ __launch_bounds__(256) void convert_bf16(const float* __restrict__ in,
                                                    unsigned short* __restrict__ out, int n) {
    int i = (blockIdx.x * 256 + threadIdx.x) * 4;
    const int stride = gridDim.x * 1024;
    for (; i < n; i += stride) {
        float4 f = *(const float4*)(in + i);
        ushort4 o;
        o.x = f2bf(f.x); o.y = f2bf(f.y); o.z = f2bf(f.z); o.w = f2bf(f.w);
        *(ushort4*)(out + i) = o;
    }
}

// ---------------- fp32 [K][N] -> bf16 [N][K] (W^T) ----------------
__global__ __launch_bounds__(256) void transpose_bf16(const float* __restrict__ W,
                                                      unsigned short* __restrict__ Wt,
                                                      int K, int N) {
    __shared__ float tile[64][65];
    const int k0 = blockIdx.y << 6;
    const int n0 = blockIdx.x << 6;
    const int rr = threadIdx.x >> 4;
    const int cc = (threadIdx.x & 15) << 2;
#pragma unroll
    for (int i = 0; i < 4; i++) {
        int r = rr + (i << 4);
        *(float4*)&tile[r][cc] = *(const float4*)(W + (size_t)(k0 + r) * N + n0 + cc);
    }
    __syncthreads();
#pragma unroll
    for (int i = 0; i < 4; i++) {
        int nr = rr + (i << 4);
        ushort4 o;
        o.x = f2bf(tile[cc + 0][nr]);
        o.y = f2bf(tile[cc + 1][nr]);
        o.z = f2bf(tile[cc + 2][nr]);
        o.w = f2bf(tile[cc + 3][nr]);
        *(ushort4*)(Wt + (size_t)(n0 + nr) * K + k0 + cc) = o;
    }
}

// ---------------- bf16 MFMA GEMM: qkv = X @ Wt^T + bias -> bf16 q/k/vT -----
__global__ __launch_bounds__(256) void gemm_qkv(const unsigned short* __restrict__ A,
                                                const unsigned short* __restrict__ Bt,
                                                const float* __restrict__ bias,
                                                unsigned short* __restrict__ qb,
                                                unsigned short* __restrict__ kb,
                                                unsigned short* __restrict__ vt) {
    const int K = 1024;
    __shared__ short As[128][40];
    __shared__ short Bs[128][40];
    const int tid  = threadIdx.x;
    const int lane = tid & 63, wave = tid >> 6;
    const int ln   = lane & 15, quad = lane >> 4;
    const int wm   = wave & 1,  wn   = wave >> 1;
    const int row0 = blockIdx.y << 7;
    const int col0 = blockIdx.x << 7;
    floatx4 acc[4][4];
#pragma unroll
    for (int i = 0; i < 4; i++)
#pragma unroll
        for (int j = 0; j < 4; j++) acc[i][j] = (floatx4){0.f, 0.f, 0.f, 0.f};

    for (int k0 = 0; k0 < K; k0 += 32) {
#pragma unroll
        for (int cc = 0; cc < 2; cc++) {
            int c = (cc << 8) + tid;
            int r = c >> 2, q = c & 3;
            *(bf16x8*)&As[r][q << 3] = *(const bf16x8*)(A  + (size_t)(row0 + r) * K + k0 + (q << 3));
            *(bf16x8*)&Bs[r][q << 3] = *(const bf16x8*)(Bt + (size_t)(col0 + r) * K + k0 + (q << 3));
        }
        __syncthreads();
        bf16x8 af[4], bfr[4];
#pragma unroll
        for (int t = 0; t < 4; t++) af[t]  = *(bf16x8*)&As[(wm << 6) + (t << 4) + ln][quad << 3];
#pragma unroll
        for (int t = 0; t < 4; t++) bfr[t] = *(bf16x8*)&Bs[(wn << 6) + (t << 4) + ln][quad << 3];
#pragma unroll
        for (int mt = 0; mt < 4; mt++)
#pragma unroll
            for (int nt = 0; nt < 4; nt++)
                acc[mt][nt] = __builtin_amdgcn_mfma_f32_16x16x32_bf16(af[mt], bfr[nt], acc[mt][nt], 0, 0, 0);
        __syncthreads();
    }
#pragma unroll
    for (int mt = 0; mt < 4; mt++) {
#pragma unroll
        for (int nt = 0; nt < 4; nt++) {
            int n = col0 + (wn << 6) + (nt << 4) + ln;
            int h = n / 192, r = n % 192;
            int sel = r >> 6, d = r & 63;
            float bv = bias[n];
#pragma unroll
            for (int e = 0; e < 4; e++) {
                int m = row0 + (wm << 6) + (mt << 4) + (quad << 2) + e;
                int b = m >> 11, t = m & 2047;
                float val = acc[mt][nt][e] + bv;
                int bh = b * NH + h;
                if (sel == 0)
                    qb[((size_t)bh * T_SEQ + t) * HD + d] = f2bf(val * 0.125f);
                else if (sel == 1)
                    kb[((size_t)bh * T_SEQ + t) * HD + d] = f2bf(val);
                else
                    vt[((size_t)bh * HD + d) * T_SEQ + t] = f2bf(val);
            }
        }
    }
}

// ---------------- bf16 MFMA GEMM: out = Y @ WoutT^T + bias (fp32 out) -------
__global__ __launch_bounds__(256) void gemm_out(const unsigned short* __restrict__ A,
                                                const unsigned short* __restrict__ Bt,
                                                const float* __restrict__ bias,
                                                float* __restrict__ out) {
    const int K = 1024, N = 1024;
    __shared__ short As[128][40];
    __shared__ short Bs[128][40];
    const int tid  = threadIdx.x;
    const int lane = tid & 63, wave = tid >> 6;
    const int ln   = lane & 15, quad = lane >> 4;
    const int wm   = wave & 1,  wn   = wave >> 1;
    const int row0 = blockIdx.y << 7;
    const int col0 = blockIdx.x << 7;
    floatx4 acc[4][4];
#pragma unroll
    for (int i = 0; i < 4; i++)
#pragma unroll
        for (int j = 0; j < 4; j++) acc[i][j] = (floatx4){0.f, 0.f, 0.f, 0.f};

    for (int k0 = 0; k0 < K; k0 += 32) {
#pragma unroll
        for (int cc = 0; cc < 2; cc++) {
            int c = (cc << 8) + tid;
            int r = c >> 2, q = c & 3;
            *(bf16x8*)&As[r][q << 3] = *(const bf16x8*)(A  + (size_t)(row0 + r) * K + k0 + (q << 3));
            *(bf16x8*)&Bs[r][q << 3] = *(const bf16x8*)(Bt + (size_t)(col0 + r) * K + k0 + (q << 3));
        }
        __syncthreads();
        bf16x8 af[4], bfr[4];
#pragma unroll
        for (int t = 0; t < 4; t++) af[t]  = *(bf16x8*)&As[(wm << 6) + (t << 4) + ln][quad << 3];
#pragma unroll
        for (int t = 0; t < 4; t++) bfr[t] = *(bf16x8*)&Bs[(wn << 6) + (t << 4) + ln][quad << 3];
#pragma unroll
        for (int mt = 0; mt < 4; mt++)
#pragma unroll
            for (int nt = 0; nt < 4; nt++)
                acc[mt][nt] = __builtin_amdgcn_mfma_f32_16x16x32_bf16(af[mt], bfr[nt], acc[mt][nt], 0, 0, 0);
        __syncthreads();
    }
#pragma unroll
    for (int mt = 0; mt < 4; mt++) {
#pragma unroll
        for (int nt = 0; nt < 4; nt++) {
            int n = col0 + (wn << 6) + (nt << 4) + ln;
            float bv = bias[n];
#pragma unroll
            for (int e = 0; e < 4; e++) {
                int m = row0 + (wm << 6) + (mt << 4) + (quad << 2) + e;
                out[(size_t)m * N + n] = acc[mt][nt][e] + bv;
            }
        }
    }
}

// ---------------- MFMA flash attention v4: transposed-S softmax ----------
// Q-tile 64, K-tile 64, 4 waves; wave w owns q-rows [16w,16w+16).
// S^T = K·Q^T  (A=K-frag, B=Q-frag): lane holds q=ln, k=16ktl+4quad+e.
// Softmax: in-register reduce(16) + 2 shfl_xor. P written [q][k] with b64
// stores (contiguous k), read back as standard PV A-frag (b128). PV B=V^T.
// Stats (m,l,alpha) live per-lane at q=ln; alpha moved to row layout by 4
// bpermutes. Diagonal tile: wave w computes only ktl<=w subtiles.
__global__ __launch_bounds__(256, 4) void attn(const unsigned short* __restrict__ qb,
                                               const unsigned short* __restrict__ kb,
                                               const unsigned short* __restrict__ vt,
                                               unsigned short* __restrict__ y) {
    __shared__ short Ks[64][72];    // [k-row][d]
    __shared__ short Vs[64][72];    // [d][k-col]  (from vt)
    __shared__ short QP[64][72];    // Q staging pre-loop, then P[q][k] (wave-private rows)
    const int tid  = threadIdx.x;
    const int w    = tid >> 6, lane = tid & 63;
    const int ln   = lane & 15, quad = lane >> 4;
    const int qt   = 31 - (int)blockIdx.x;          // LPT: long blocks first
    const int bh   = blockIdx.y;
    const size_t base = (size_t)bh * T_SEQ * HD;
    const int q0   = qt << 6;
    const int sb   = q0 + (w << 4);                 // this wave's first q-row
    const float NEG_INF = -__builtin_inff();

    const int sr = tid >> 3;          // staging row 0..31 (+32)
    const int sc = (tid & 7) << 3;    // staging col (bf16x8)

    // stage Q -> QP, prefetch K/V tile 0 into regs
    bf16x8 qtmp[2], kreg[2], vreg[2];
#pragma unroll
    for (int i = 0; i < 2; i++) {
        qtmp[i] = *(const bf16x8*)(qb + base + (size_t)(q0 + sr + (i << 5)) * HD + sc);
        kreg[i] = *(const bf16x8*)(kb + base + (size_t)(sr + (i << 5)) * HD + sc);
        vreg[i] = *(const bf16x8*)(vt + base + (size_t)(sr + (i << 5)) * T_SEQ + sc);
    }
#pragma unroll
    for (int i = 0; i < 2; i++) *(bf16x8*)&QP[sr + (i << 5)][sc] = qtmp[i];
    __syncthreads();

    // hoist loop-invariant Q B-frags (wave-private rows; safe to overwrite with P later)
    bf16x8 bq0 = *(bf16x8*)&QP[(w << 4) + ln][quad << 3];
    bf16x8 bq1 = *(bf16x8*)&QP[(w << 4) + ln][32 + (quad << 3)];

    floatx4 o[4];
#pragma unroll
    for (int nt = 0; nt < 4; nt++) o[nt] = (floatx4){0.f, 0.f, 0.f, 0.f};
    float m_prev = NEG_INF, l_run = 0.f;            // per-lane stats for q = sb+ln

    for (int kt = 0; kt <= qt; kt++) {
        const int k0 = kt << 6;
        __syncthreads();                            // prev-iter Ks/Vs reads done
#pragma unroll
        for (int i = 0; i < 2; i++) {
            *(bf16x8*)&Ks[sr + (i << 5)][sc] = kreg[i];
            *(bf16x8*)&Vs[sr + (i << 5)][sc] = vreg[i];
        }
        __syncthreads();
        if (kt < qt) {                              // prefetch next tile behind compute
            const int kn = k0 + 64;
#pragma unroll
            for (int i = 0; i < 2; i++) {
                kreg[i] = *(const bf16x8*)(kb + base + (size_t)(kn + sr + (i << 5)) * HD + sc);
                vreg[i] = *(const bf16x8*)(vt + base + (size_t)(sr + (i << 5)) * T_SEQ + kn + sc);
            }
        }

        const bool diag  = (kt == qt);
        const int  nlive = diag ? w : 3;            // wave-uniform

        // S^T subtiles: st[ktl] holds k=k0+16ktl+4quad+e, q=sb+ln
        floatx4 st[4];
#pragma unroll
        for (int ktl = 0; ktl < 4; ktl++) {
            if (ktl <= nlive) {
                bf16x8 a0 = *(bf16x8*)&Ks[(ktl << 4) + ln][quad << 3];
                bf16x8 a1 = *(bf16x8*)&Ks[(ktl << 4) + ln][32 + (quad << 3)];
                floatx4 acc = (floatx4){0.f, 0.f, 0.f, 0.f};
                acc = __builtin_amdgcn_mfma_f32_16x16x32_bf16(a0, bq0, acc, 0, 0, 0);
                acc = __builtin_amdgcn_mfma_f32_16x16x32_bf16(a1, bq1, acc, 0, 0, 0);
                st[ktl] = acc;
            }
        }
        // causal mask (diagonal tile only)
        if (diag) {
#pragma unroll
            for (int ktl = 0; ktl < 4; ktl++) {
                if (ktl <= nlive) {
#pragma unroll
                    for (int e = 0; e < 4; e++) {
                        int kg = k0 + (ktl << 4) + (quad << 2) + e;
                        if (kg > sb + ln) st[ktl][e] = NEG_INF;
                    }
                }
            }
        }

        // online softmax for q=sb+ln: in-register + 2 shfls each
        float mx = NEG_INF;
#pragma unroll
        for (int ktl = 0; ktl < 4; ktl++)
            if (ktl <= nlive) {
#pragma unroll
                for (int e = 0; e < 4; e++) mx = fmaxf(mx, st[ktl][e]);
            }
        mx = fmaxf(mx, __shfl_xor(mx, 16));
        mx = fmaxf(mx, __shfl_xor(mx, 32));
        float m_new = fmaxf(m_prev, mx);
        float alpha = __expf(m_prev - m_new);
        float psum = 0.f;
#pragma unroll
        for (int ktl = 0; ktl < 4; ktl++)
            if (ktl <= nlive) {
#pragma unroll
                for (int e = 0; e < 4; e++) {
                    float p = __expf(st[ktl][e] - m_new);
                    st[ktl][e] = p;
                    psum += p;
                }
            }
        psum += __shfl_xor(psum, 16);
        psum += __shfl_xor(psum, 32);
        l_run = l_run * alpha + psum;
        m_prev = m_new;

        // P -> QP[q][k], b64 stores, contiguous k (wave-private row 16w+ln)
#pragma unroll
        for (int ktl = 0; ktl < 4; ktl++) {
            ushort4 pw;
            if (ktl <= nlive) {
                pw.x = f2bf(st[ktl][0]); pw.y = f2bf(st[ktl][1]);
                pw.z = f2bf(st[ktl][2]); pw.w = f2bf(st[ktl][3]);
            } else {
                pw.x = 0; pw.y = 0; pw.z = 0; pw.w = 0;
            }
            *(ushort4*)&QP[(w << 4) + ln][(ktl << 4) + (quad << 2)] = pw;
        }

        // alpha to row layout (rows q=sb+4quad+e), rescale O
        float arow[4];
#pragma unroll
        for (int e = 0; e < 4; e++) arow[e] = __shfl(alpha, (quad << 2) + e);
#pragma unroll
        for (int nt = 0; nt < 4; nt++)
#pragma unroll
            for (int e = 0; e < 4; e++) o[nt][e] *= arow[e];

        // PV: A = P (wave-private rows, no barrier needed), B = V^T
        bf16x8 ap0 = *(bf16x8*)&QP[(w << 4) + ln][quad << 3];
        bf16x8 ap1 = *(bf16x8*)&QP[(w << 4) + ln][32 + (quad << 3)];
#pragma unroll
        for (int nt = 0; nt < 4; nt++) {
            bf16x8 v0 = *(bf16x8*)&Vs[(nt << 4) + ln][quad << 3];
            bf16x8 v1 = *(bf16x8*)&Vs[(nt << 4) + ln][32 + (quad << 3)];
            o[nt] = __builtin_amdgcn_mfma_f32_16x16x32_bf16(ap0, v0, o[nt], 0, 0, 0);
            o[nt] = __builtin_amdgcn_mfma_f32_16x16x32_bf16(ap1, v1, o[nt], 0, 0, 0);
        }
    }

    // epilogue: y[b, t, h*64+d] bf16; l to row layout via 4 bpermutes
    float linv[4];
#pragma unroll
    for (int e = 0; e < 4; e++) linv[e] = 1.0f / __shfl(l_run, (quad << 2) + e);
    const int b = bh >> 4, h = bh & 15;
#pragma unroll
    for (int e = 0; e < 4; e++) {
        int t = sb + (quad << 2) + e;
        unsigned short* yrow = y + ((size_t)b * T_SEQ + t) * C_DIM + h * HD;
#pragma unroll
        for (int nt = 0; nt < 4; nt++)
            yrow[(nt << 4) + ln] = f2bf(o[nt][e] * linv[e]);
    }
}

extern "C" void kernel_launch(void* const* d_in, const int* in_sizes, int n_in,
                              void* d_out, int out_size, void* d_ws, size_t ws_size,
                              hipStream_t stream) {
    (void)in_sizes; (void)n_in; (void)out_size; (void)ws_size;
    const float* x     = (const float*)d_in[0];
    const float* w_qkv = (const float*)d_in[1];
    const float* b_qkv = (const float*)d_in[2];
    const float* w_out = (const float*)d_in[3];
    const float* b_out = (const float*)d_in[4];
    float* out = (float*)d_out;

    char* ws = (char*)d_ws;
    unsigned short* qb    = (unsigned short*)ws;                        // 8 MB
    unsigned short* kb    = (unsigned short*)(ws + ((size_t)8  << 20)); // 8 MB
    unsigned short* vt    = (unsigned short*)(ws + ((size_t)16 << 20)); // 8 MB
    unsigned short* xb    = (unsigned short*)(ws + ((size_t)24 << 20)); // 8 MB (alias yb)
    unsigned short* yb    = xb;
    unsigned short* wqkvT = (unsigned short*)(ws + ((size_t)32 << 20)); // 6 MB
    unsigned short* woutT = (unsigned short*)(ws + ((size_t)38 << 20)); // 2 MB

    convert_bf16  <<<1024, 256, 0, stream>>>(x, xb, BT * C_DIM);
    transpose_bf16<<<dim3(48, 16), 256, 0, stream>>>(w_qkv, wqkvT, 1024, 3072);
    transpose_bf16<<<dim3(16, 16), 256, 0, stream>>>(w_out, woutT, 1024, 1024);
    gemm_qkv      <<<dim3(24, 32), 256, 0, stream>>>(xb, wqkvT, b_qkv, qb, kb, vt);
    attn          <<<dim3(32, 32), 256, 0, stream>>>(qb, kb, vt, yb);
    gemm_out      <<<dim3(8, 32), 256, 0, stream>>>(yb, woutT, b_out, out);
}